// Round 7
// baseline (41.774 us; speedup 1.0000x reference)
//
#include <hip/hip_runtime.h>

#define FF 7
#define BLOCK 128
#define PIX_PER_THREAD 4
#define PIX_PER_BLOCK (BLOCK * PIX_PER_THREAD)          // 512 pixels
#define V4_PER_BLOCK (PIX_PER_BLOCK * FF / 4)            // 896 float4 = 14 KB

typedef float vfloat4 __attribute__((ext_vector_type(4)));

__global__ __launch_bounds__(BLOCK) void fused_scale_matmul_kernel(
    const float* __restrict__ x,   // [npix * 7]
    const float* __restrict__ d,   // [npix]
    const float* __restrict__ W,   // [7 * 7]
    float* __restrict__ out,       // [npix * 7]
    int npix)
{
    __shared__ float lds[PIX_PER_BLOCK * FF];            // 14 KB, reused in+out
    vfloat4* ldsv = reinterpret_cast<vfloat4*>(lds);

    // W: uniform address -> scalar (SGPR) loads, broadcast to all lanes.
    float w[FF][FF];
#pragma unroll
    for (int f = 0; f < FF; ++f)
#pragma unroll
        for (int g = 0; g < FF; ++g)
            w[f][g] = W[f * FF + g];

    const int tid = threadIdx.x;
    const long long blockPix = (long long)blockIdx.x * PIX_PER_BLOCK;
    if (blockPix >= npix) return;
    const long long base4 = (long long)blockIdx.x * V4_PER_BLOCK;

    // Stage-in: 7 float4 loads per thread, each instruction fully contiguous
    // per wave (64 lanes x 16B = 1 KB per instruction).
    const vfloat4* xg = reinterpret_cast<const vfloat4*>(x);
#pragma unroll
    for (int k = 0; k < FF; ++k)
        ldsv[k * BLOCK + tid] = xg[base4 + k * BLOCK + tid];

    // d: naturally coalesced float4 (lane i -> 4 consecutive pixels).
    vfloat4 dv = *reinterpret_cast<const vfloat4*>(d + blockPix + tid * PIX_PER_THREAD);
    float dd[PIX_PER_THREAD] = {dv.x, dv.y, dv.z, dv.w};

    __syncthreads();

    // Redistribute: each thread reads its 4 pixels (28 floats) from LDS.
    float xs[PIX_PER_THREAD * FF];
    vfloat4* xv = reinterpret_cast<vfloat4*>(xs);
#pragma unroll
    for (int k = 0; k < FF; ++k)
        xv[k] = ldsv[tid * FF + k];

    float ov[PIX_PER_THREAD * FF];
#pragma unroll
    for (int p = 0; p < PIX_PER_THREAD; ++p) {
#pragma unroll
        for (int g = 0; g < FF; ++g) {
            float acc = 0.0f;
#pragma unroll
            for (int f = 0; f < FF; ++f)
                acc = fmaf(xs[p * FF + f], w[f][g], acc);
            ov[p * FF + g] = dd[p] * acc;
        }
    }

    __syncthreads();

    // Stage-out through the same LDS buffer.
    const vfloat4* os = reinterpret_cast<const vfloat4*>(ov);
#pragma unroll
    for (int k = 0; k < FF; ++k)
        ldsv[tid * FF + k] = os[k];

    __syncthreads();

    // Coalesced non-temporal stores: each wave-instruction covers 16 fully
    // written 64B lines, so nt cannot amplify (verified round 6: WRITE_SIZE
    // unchanged vs write-back).
    vfloat4* og = reinterpret_cast<vfloat4*>(out);
#pragma unroll
    for (int k = 0; k < FF; ++k)
        __builtin_nontemporal_store(ldsv[k * BLOCK + tid],
                                    og + base4 + k * BLOCK + tid);
}

extern "C" void kernel_launch(void* const* d_in, const int* in_sizes, int n_in,
                              void* d_out, int out_size, void* d_ws, size_t ws_size,
                              hipStream_t stream) {
    const float* x = (const float*)d_in[0];
    const float* d = (const float*)d_in[1];
    const float* W = (const float*)d_in[2];
    float* out = (float*)d_out;

    int npix = in_sizes[1];  // H * W = 2048 * 2048
    int nblocks = (npix + PIX_PER_BLOCK - 1) / PIX_PER_BLOCK;  // 8192

    hipLaunchKernelGGL(fused_scale_matmul_kernel,
                       dim3(nblocks), dim3(BLOCK), 0, stream,
                       x, d, W, out, npix);
}